// Round 2
// baseline (10687.411 us; speedup 1.0000x reference)
//
#include <hip/hip_runtime.h>
#include <cmath>

constexpr int SEQ = 64;    // sequence length
constexpr int NB  = 128;   // batch
constexpr int H   = 256;   // hidden
constexpr int DIN = 128;   // composed token dim
constexpr int DE  = 256;   // word emb dim
constexpr int NA  = 64;    // actions
constexpr int S1  = 41;    // STACK_SIZE+1
constexpr int MS  = 100;   // max steps
constexpr int G4  = 1024;  // 4*H

__device__ __forceinline__ float sigf(float x){ return 1.0f/(1.0f+expf(-x)); }

// ---------------- transpose: in [R][C] -> out [C][R]
__global__ void transpose_k(const float* __restrict__ in, float* __restrict__ out,
                            int R, int C){
  __shared__ float t[32][33];
  int bx = blockIdx.x*32, by = blockIdx.y*32;
  int x = threadIdx.x, y = threadIdx.y;   // block 32x8
  #pragma unroll
  for (int j = 0; j < 32; j += 8)
    t[y+j][x] = in[(size_t)(by+y+j)*C + bx + x];
  __syncthreads();
  #pragma unroll
  for (int j = 0; j < 32; j += 8)
    out[(size_t)(bx+y+j)*R + by + x] = t[x][y+j];
}

// hist_xz[a][r] = hist_Wih[r,:] . action_emb[a,:] + hist_bih[r] + hist_bhh[r]
__global__ void hist_proj_kernel(const float* __restrict__ Wih,
                                 const float* __restrict__ bih,
                                 const float* __restrict__ bhh,
                                 const float* __restrict__ aemb,
                                 float* __restrict__ out){
  int a = blockIdx.x, t = threadIdx.x;
  __shared__ float e[64];
  if (t < 64) e[t] = aemb[a*64 + t];
  __syncthreads();
  for (int r = t; r < G4; r += blockDim.x){
    const float* w = Wih + r*64;
    float acc = bih[r] + bhh[r];
    #pragma unroll
    for (int k = 0; k < 64; k += 4)
      acc += w[k]*e[k] + w[k+1]*e[k+1] + w[k+2]*e[k+2] + w[k+3]*e[k+3];
    out[a*G4 + r] = acc;
  }
}

// one-time projections of h0 (element-independent):
// pz0 = st_Whh @ h0 ; psum0 = Wsum_s @ h0 (f64) ; ysumb0 = Wsum_b @ h0
__global__ void h0_proj_kernel(const float* __restrict__ Wt_st,   // [256][1024]
                               const float* __restrict__ Wt_sum,  // [768][256]
                               const float* __restrict__ h0,
                               float* __restrict__ pz0,           // [1024]
                               double* __restrict__ psum0,        // [256]
                               float* __restrict__ ysumb0){       // [256]
  __shared__ float h0l[H];
  const int t = threadIdx.x;   // 256 threads
  h0l[t] = h0[t];
  __syncthreads();
  float4 acc = make_float4(0.f,0.f,0.f,0.f);
  for (int c = 0; c < H; ++c){
    float4 w = ((const float4*)(Wt_st + (size_t)c*G4))[t];
    float x = h0l[c];
    acc.x += w.x*x; acc.y += w.y*x; acc.z += w.z*x; acc.w += w.w*x;
  }
  ((float4*)pz0)[t] = acc;
  double a0 = 0.0, a1 = 0.0;
  for (int c = 0; c < H; ++c){
    double x = (double)h0l[c];
    a0 += (double)Wt_sum[(size_t)c*H + t] * x;          // s-part
    a1 += (double)Wt_sum[(size_t)(H + c)*H + t] * x;    // b-part
  }
  psum0[t] = a0;
  ysumb0[t] = (float)a1;
}

// One workgroup per batch element; 1024 threads.
// Key structural idea: cache per-stack-slot projections so the per-step weight
// stream shrinks from ~2.9MB to ~1.35MB (+1.3MB on push steps only):
//   pzs[slot]   = st_Whh  @ stack_h[slot]   (f32[1024], computed at push)
//   psums[slot] = Wsum_s  @ stack_h[slot]   (f64[256],  computed at push)
//   ysumb[j]    = Wsum_b  @ buffer_head(j)  (f32[256],  precomputed after P1)
__global__ __launch_bounds__(1024, 4)
void parser_kernel(const int* __restrict__ tokens,
                   const float* __restrict__ word_emb,
                   const float* __restrict__ Wt_cmp,   // [256][128]
                   const float* __restrict__ compose_b,
                   const float* __restrict__ h0,
                   const float* __restrict__ c0,
                   const float* __restrict__ Wt_pbih,  // [128][1024]
                   const float* __restrict__ Wt_pb,    // [256][1024]
                   const float* __restrict__ pb_bih,
                   const float* __restrict__ pb_bhh,
                   const float* __restrict__ Wt_stih,  // [128][1024]
                   const float* __restrict__ Wt_st,    // [256][1024]
                   const float* __restrict__ st_bih,
                   const float* __restrict__ st_bhh,
                   const float* __restrict__ Wt_hi,    // [256][1024]
                   const float* __restrict__ Wt_sum,   // [768][256]
                   const float* __restrict__ sum_b,
                   const float* __restrict__ Wt_act,   // [256][64]
                   const float* __restrict__ act_b,
                   const int* __restrict__ stack_map,
                   const int* __restrict__ buffer_map,
                   const float* __restrict__ histxz,   // [64][1024]
                   float* __restrict__ pb_zx,   // [B][64][1024]; arena reused for pzs/psums
                   float* __restrict__ st_zx,   // [B][65][1024] (row 64 = bias only)
                   float* __restrict__ bufh,    // [B][64][256]
                   float* __restrict__ scst,    // [B][41][256] stack c
                   float* __restrict__ ysumb_g, // [B][65][256]
                   const float* __restrict__ pz0,    // [1024]
                   const double* __restrict__ psum0, // [256]
                   const float* __restrict__ ysumb0, // [256]
                   float* __restrict__ out)     // [100][128][64]
{
  // LDS regions (aliased):
  //  A[0..4095]     : f32 partials [4][1024] (P1 matvec / AH hist / PUSH pz); P0 tokl[0..8191]
  //  A[4096..6143]  : f64 partials [4][4][64] (suma / PUSH psum)
  //  A[6144..7167]  : f64 partials [8][64]   (C logits)
  //  A[7168..7423]  : hl2 (st-LSTM candidate h2)
  __shared__ __align__(16) float A[8192];
  __shared__ __align__(16) float Bx[4096];   // P0a emb staging only
  __shared__ __align__(16) float summ[H];
  __shared__ __align__(16) float ahl[H];
  __shared__ __align__(16) float acl[H];
  __shared__ __align__(16) float h0l[H];
  __shared__ int ctl[12];

  const int b   = blockIdx.x;
  const int tid = threadIdx.x;

  float* tokl = A;               // [64][128] during P0
  float* embs = Bx;              // [16][256] during P0a

  // per-block derived pointers
  float*  pzs_b   = pb_zx + (size_t)b*SEQ*G4;            // arena (aliases own pb_zx rows)
  double* psums_b = (double*)(pzs_b + (size_t)S1*G4);    // f64[41][256], still inside arena
  float*  pbzx_b  = pb_zx + (size_t)b*SEQ*G4;            // P1 reads (same range, read before reuse)
  float*  stzx_b  = st_zx + (size_t)b*(SEQ+1)*G4;
  float*  bufh_b  = bufh  + (size_t)b*SEQ*H;
  float*  scst_b  = scst  + (size_t)b*S1*H;
  float*  ysumb_b = ysumb_g + (size_t)b*65*H;

  if (tid < H) h0l[tid] = h0[tid];
  __syncthreads();

  // ---------------- P0a: tok[t] = relu(W_c @ emb[tokens[t,b]] + b_c)
  {
    const int d = tid & 127, tb = tid >> 7;   // tb 0..7, 2 tokens each
    const float cb = compose_b[d];
    for (int pass = 0; pass < 4; ++pass){
      for (int j = tid >> 8; j < 16; j += 4){
        int tt = pass*16 + j;
        int id = tokens[tt*NB + b];
        embs[j*DE + (tid & 255)] = word_emb[(size_t)id*DE + (tid & 255)];
      }
      __syncthreads();
      float a0 = 0.f, a1 = 0.f;
      const float* eb = embs + (tb*2)*DE;
      for (int c = 0; c < DE; ++c){
        float w = Wt_cmp[c*DIN + d];
        a0 += w*eb[c]; a1 += w*eb[DE + c];
      }
      int t0 = pass*16 + tb*2;
      tokl[(t0    )*DIN + d] = fmaxf(a0 + cb, 0.f);
      tokl[(t0 + 1)*DIN + d] = fmaxf(a1 + cb, 0.f);
      __syncthreads();
    }
  }

  // ---------------- P0b: zx = Wih @ tok + (bih+bhh).  m=0: pb (tid<512), m=1: st.
  {
    const int m  = tid >> 9;
    const int lt = tid & 255;          // float4 quad over 1024 rows
    const int sub = (tid >> 8) & 1;    // token half of each 16-token blk
    const float* Wt  = m ? Wt_stih : Wt_pbih;           // [128][1024]
    float*       zxb = m ? stzx_b : pbzx_b;
    const float* bA  = m ? st_bih : pb_bih;
    const float* bB  = m ? st_bhh : pb_bhh;
    float4 x1 = ((const float4*)bA)[lt], x2 = ((const float4*)bB)[lt];
    float bx = x1.x + x2.x, by = x1.y + x2.y, bz = x1.z + x2.z, bw = x1.w + x2.w;
    for (int blk = 0; blk < 4; ++blk){
      float ax[8], ay[8], az[8], aw[8];
      #pragma unroll
      for (int t = 0; t < 8; ++t){ ax[t]=0.f; ay[t]=0.f; az[t]=0.f; aw[t]=0.f; }
      const float* tb = tokl + (blk*16 + sub*8)*DIN;
      for (int c = 0; c < DIN; ++c){
        float4 w = ((const float4*)(Wt + (size_t)c*G4))[lt];
        #pragma unroll
        for (int t = 0; t < 8; ++t){
          float x = tb[t*DIN + c];
          ax[t] += w.x*x; ay[t] += w.y*x; az[t] += w.z*x; aw[t] += w.w*x;
        }
      }
      #pragma unroll
      for (int t = 0; t < 8; ++t){
        float4 r = make_float4(ax[t]+bx, ay[t]+by, az[t]+bz, aw[t]+bw);
        ((float4*)(zxb + (size_t)(blk*16 + sub*8 + t)*G4))[lt] = r;
      }
    }
    if (m == 1 && sub == 0)
      ((float4*)(zxb + (size_t)SEQ*G4))[lt] = make_float4(bx, by, bz, bw);
  }
  __syncthreads();

  // ---------------- P1: pre-buffer LSTM over reversed tokens
  if (tid < H){ ahl[tid] = h0l[tid]; acl[tid] = c0[tid]; }
  __syncthreads();
  for (int k = 0; k < SEQ; ++k){
    const int tt = SEQ - 1 - k;
    {
      const int q = tid & 255, cg = tid >> 8;   // cg 0..3
      float a0=0.f, a1=0.f, a2=0.f, a3=0.f;
      const int cb2 = cg*64;
      for (int c = cb2; c < cb2 + 64; ++c){
        float4 w = ((const float4*)(Wt_pb + (size_t)c*G4))[q];
        float x = ahl[c];
        a0 += w.x*x; a1 += w.y*x; a2 += w.z*x; a3 += w.w*x;
      }
      ((float4*)(A + cg*G4))[q] = make_float4(a0, a1, a2, a3);
    }
    __syncthreads();
    if (tid < H){
      const float* zx = pbzx_b + (size_t)tt*G4;
      float zi_ = A[tid]     + A[G4+tid]     + A[2*G4+tid]     + A[3*G4+tid]     + zx[tid];
      float zf_ = A[H+tid]   + A[G4+H+tid]   + A[2*G4+H+tid]   + A[3*G4+H+tid]   + zx[H+tid];
      float zg_ = A[2*H+tid] + A[G4+2*H+tid] + A[2*G4+2*H+tid] + A[3*G4+2*H+tid] + zx[2*H+tid];
      float zo_ = A[3*H+tid] + A[G4+3*H+tid] + A[2*G4+3*H+tid] + A[3*G4+3*H+tid] + zx[3*H+tid];
      float c2 = sigf(zf_)*acl[tid] + sigf(zi_)*tanhf(zg_);
      float h2 = sigf(zo_)*tanhf(c2);
      acl[tid] = c2; ahl[tid] = h2;
      bufh_b[(size_t)k*H + tid] = h2;
    }
    __syncthreads();
  }
  // P1 done: pb_zx rows of this block are dead; arena (pzs/psums) may be written.

  // ---------------- main init + ysumb precompute
  if (tid < 256) ((float4*)pzs_b)[tid] = ((const float4*)pz0)[tid];   // pzs[0]
  if (tid < 256) psums_b[tid] = psum0[tid];                           // psums[0]
  if (tid < 64)  ((float4*)ysumb_b)[tid] = ((const float4*)ysumb0)[tid]; // ysumb[0]
  for (int i = tid; i < S1*H; i += 1024) scst_b[i] = (i < H) ? c0[i] : 0.f;
  if (tid < H){ ahl[tid] = h0l[tid]; acl[tid] = c0[tid]; }   // hist LSTM state (ahl currently buf_h[63]; reset)
  if (tid == 0){ ctl[0] = 0; ctl[1] = SEQ; ctl[2] = SEQ - 1; } // spos, bpos, sin_idx

  // ysumb[j] = Wsum_b @ bufh[j-1], j=1..64.  f64 accumulate, f32 store.
  // wave wv handles j = wv+1, wv+17, wv+33, wv+49 (x reads are wave-uniform).
  {
    const int lt = tid & 63, wv = tid >> 6;
    double a00=0,a01=0,a02=0,a03=0, a10=0,a11=0,a12=0,a13=0;
    double a20=0,a21=0,a22=0,a23=0, a30=0,a31=0,a32=0,a33=0;
    for (int c = 0; c < H; ++c){
      float4 w = ((const float4*)(Wt_sum + (size_t)(H + c)*H))[lt];
      double x0 = (double)bufh_b[(size_t)(wv     )*H + c];
      double x1 = (double)bufh_b[(size_t)(wv + 16)*H + c];
      double x2 = (double)bufh_b[(size_t)(wv + 32)*H + c];
      double x3 = (double)bufh_b[(size_t)(wv + 48)*H + c];
      a00+=(double)w.x*x0; a01+=(double)w.y*x0; a02+=(double)w.z*x0; a03+=(double)w.w*x0;
      a10+=(double)w.x*x1; a11+=(double)w.y*x1; a12+=(double)w.z*x1; a13+=(double)w.w*x1;
      a20+=(double)w.x*x2; a21+=(double)w.y*x2; a22+=(double)w.z*x2; a23+=(double)w.w*x2;
      a30+=(double)w.x*x3; a31+=(double)w.y*x3; a32+=(double)w.z*x3; a33+=(double)w.w*x3;
    }
    ((float4*)(ysumb_b + (size_t)(wv+ 1)*H))[lt] = make_float4((float)a00,(float)a01,(float)a02,(float)a03);
    ((float4*)(ysumb_b + (size_t)(wv+17)*H))[lt] = make_float4((float)a10,(float)a11,(float)a12,(float)a13);
    ((float4*)(ysumb_b + (size_t)(wv+33)*H))[lt] = make_float4((float)a20,(float)a21,(float)a22,(float)a23);
    ((float4*)(ysumb_b + (size_t)(wv+49)*H))[lt] = make_float4((float)a30,(float)a31,(float)a32,(float)a33);
  }
  __syncthreads();

  // ---------------- main parser loop
  for (int step = 0; step < MS; ++step){
    const int spos = ctl[0], bposc = ctl[1], sinc = ctl[2];

    // prefetches (held in registers across barriers)
    float g_pz0=0.f,g_pz1=0.f,g_pz2=0.f,g_pz3=0.f;
    float g_zx0=0.f,g_zx1=0.f,g_zx2=0.f,g_zx3=0.f;
    float g_ct=0.f;
    if (tid >= 512 && tid < 768){
      const int hh = tid - 512;
      const float* pzr = pzs_b + (size_t)spos*G4;
      const float* zxr = stzx_b + (size_t)sinc*G4;
      g_pz0 = pzr[hh]; g_pz1 = pzr[H+hh]; g_pz2 = pzr[2*H+hh]; g_pz3 = pzr[3*H+hh];
      g_zx0 = zxr[hh]; g_zx1 = zxr[H+hh]; g_zx2 = zxr[2*H+hh]; g_zx3 = zxr[3*H+hh];
      g_ct  = scst_b[(size_t)spos*H + hh];
    }
    double g_ps = 0.0; float g_yb = 0.f;
    if (tid < 256){
      g_ps = psums_b[(size_t)spos*H + tid];
      g_yb = ysumb_b[(size_t)bposc*H + tid];
    }

    // AH: hist z partials (all threads) + suma f64 partials (tid<256)
    {
      const int q = tid & 255, cg = tid >> 8;
      float a0=0.f, a1=0.f, a2=0.f, a3=0.f;
      const int cb2 = cg*64;
      for (int c = cb2; c < cb2 + 64; ++c){
        float4 w = ((const float4*)(Wt_hi + (size_t)c*G4))[q];
        float x = ahl[c];
        a0 += w.x*x; a1 += w.y*x; a2 += w.z*x; a3 += w.w*x;
      }
      ((float4*)(A + cg*G4))[q] = make_float4(a0, a1, a2, a3);
    }
    if (tid < 256){
      const int lt = tid & 63, cg = tid >> 6;
      double a0=0.0,a1=0.0,a2=0.0,a3=0.0;
      const int cb2 = cg*64;
      for (int c = cb2; c < cb2 + 64; ++c){
        float4 w = ((const float4*)(Wt_sum + (size_t)(512+c)*H))[lt];
        double x = (double)ahl[c];
        a0 += (double)w.x*x; a1 += (double)w.y*x;
        a2 += (double)w.z*x; a3 += (double)w.w*x;
      }
      double* pd = (double*)(A + 4096);   // layout [cg][i][lt]
      pd[(cg*4+0)*64 + lt] = a0;
      pd[(cg*4+1)*64 + lt] = a1;
      pd[(cg*4+2)*64 + lt] = a2;
      pd[(cg*4+3)*64 + lt] = a3;
    }
    __syncthreads();                                   // bar1

    // B-final: summ = relu(psums[spos] + ysumb[bposc] + suma + sum_b)
    if (tid < 256){
      const double* pd = (const double*)(A + 4096);
      const int lt = tid >> 2, i = tid & 3;
      double s = pd[(0*4+i)*64 + lt] + pd[(1*4+i)*64 + lt]
               + pd[(2*4+i)*64 + lt] + pd[(3*4+i)*64 + lt]
               + g_ps + (double)g_yb + (double)sum_b[tid];
      summ[tid] = fmaxf((float)s, 0.f);
    }
    __syncthreads();                                   // bar2

    // C partials: 8-way c-split over threads 0-511, f64
    if (tid < 512){
      const int o = tid & 63, cg = tid >> 6;
      double acc = 0.0;
      const int cb2 = cg*32;
      for (int c = cb2; c < cb2 + 32; ++c)
        acc += (double)Wt_act[c*NA + o] * (double)summ[c];
      ((double*)(A + 6144))[cg*64 + o] = acc;
    }
    __syncthreads();                                   // bar3

    // C-final (wave 0) || st-LSTM gates (threads 512-767, prefetched inputs)
    float stc2 = 0.f;
    if (tid < 64){
      const double* pc = (const double*)(A + 6144);
      double acc = (double)act_b[tid];
      #pragma unroll
      for (int g = 0; g < 8; ++g) acc += pc[g*64 + tid];
      float v = (float)acc;
      float mx = v;
      #pragma unroll
      for (int o = 32; o > 0; o >>= 1) mx = fmaxf(mx, __shfl_xor(mx, o));
      float ex = expf(v - mx), sm = ex;
      #pragma unroll
      for (int o = 32; o > 0; o >>= 1) sm += __shfl_xor(sm, o);
      out[(((size_t)step*NB) + b)*NA + tid] = v - mx - logf(sm);
      float bv = v; int bi = tid;     // argmax, first index wins on ties
      #pragma unroll
      for (int o = 32; o > 0; o >>= 1){
        float ov = __shfl_xor(bv, o); int oi = __shfl_xor(bi, o);
        if (ov > bv || (ov == bv && oi < bi)){ bv = ov; bi = oi; }
      }
      if (tid == 0){
        int a = bi;
        int sop = stack_map[a], bop = buffer_map[a];
        if (spos == 0 && sop == -1) sop = 0;
        if (spos >= S1 - 1 && sop == 1) sop = 0;
        if (bposc == 0 && bop == -1) bop = 0;
        int push  = (sop == 1) ? 1 : 0;
        int widx  = (spos + 1 < S1 - 1) ? spos + 1 : S1 - 1;
        int sposn = spos + sop;
        int bposn = bposc + bop;
        int ne    = (bposn > 0) ? 1 : 0;
        int gidx  = bposn - 1; if (gidx < 0) gidx = 0; if (gidx > SEQ - 1) gidx = SEQ - 1;
        ctl[3] = a; ctl[4] = push; ctl[5] = widx; ctl[6] = sposn;
        ctl[7] = bposn; ctl[8] = ne; ctl[9] = gidx;
      }
    } else if (tid >= 512 && tid < 768){
      const int hh = tid - 512;
      float zi_ = g_pz0 + g_zx0;
      float zf_ = g_pz1 + g_zx1;
      float zg_ = g_pz2 + g_zx2;
      float zo_ = g_pz3 + g_zx3;
      float c2 = sigf(zf_)*g_ct + sigf(zi_)*tanhf(zg_);
      float h2 = sigf(zo_)*tanhf(c2);
      stc2 = c2;
      A[7168 + hh] = h2;   // hl2
    }
    __syncthreads();                                   // bar4

    // E: hist gates + conditional stack commit + control update
    const int a_ = ctl[3], push = ctl[4], widx = ctl[5];
    if (tid >= 256 && tid < 512){
      const int hh = tid - 256;
      const float* hb = histxz + (size_t)a_*G4;
      float zi_ = ((A[hh]       + A[G4+hh])       + (A[2*G4+hh]       + A[3*G4+hh]))       + hb[hh];
      float zf_ = ((A[H+hh]     + A[G4+H+hh])     + (A[2*G4+H+hh]     + A[3*G4+H+hh]))     + hb[H+hh];
      float zg_ = ((A[2*H+hh]   + A[G4+2*H+hh])   + (A[2*G4+2*H+hh]   + A[3*G4+2*H+hh]))   + hb[2*H+hh];
      float zo_ = ((A[3*H+hh]   + A[G4+3*H+hh])   + (A[2*G4+3*H+hh]   + A[3*G4+3*H+hh]))   + hb[3*H+hh];
      float c2 = sigf(zf_)*acl[hh] + sigf(zi_)*tanhf(zg_);
      float h2 = sigf(zo_)*tanhf(c2);
      acl[hh] = c2; ahl[hh] = h2;
    } else if (tid >= 512 && tid < 768){
      if (push) scst_b[(size_t)widx*H + (tid - 512)] = stc2;
    } else if (tid == 0){
      ctl[0] = ctl[6]; ctl[1] = ctl[7]; ctl[2] = ctl[8] ? ctl[9] : SEQ;
    }
    __syncthreads();                                   // bar5

    // PUSH: compute & cache projections of the newly pushed h2 (push steps only)
    if (push){
      {
        const int q = tid & 255, cg = tid >> 8;
        float a0=0.f, a1=0.f, a2=0.f, a3=0.f;
        const float* h2v = A + 7168;
        const int cb2 = cg*64;
        for (int c = cb2; c < cb2 + 64; ++c){
          float4 w = ((const float4*)(Wt_st + (size_t)c*G4))[q];
          float x = h2v[c];
          a0 += w.x*x; a1 += w.y*x; a2 += w.z*x; a3 += w.w*x;
        }
        ((float4*)(A + cg*G4))[q] = make_float4(a0, a1, a2, a3);
        // note: writes land in A[0..4095]; hist partials already consumed.
      }
      if (tid < 256){
        const int lt = tid & 63, cg = tid >> 6;
        double a0=0.0,a1=0.0,a2=0.0,a3=0.0;
        const float* h2v = A + 7168;
        const int cb2 = cg*64;
        for (int c = cb2; c < cb2 + 64; ++c){
          float4 w = ((const float4*)(Wt_sum + (size_t)c*H))[lt];
          double x = (double)h2v[c];
          a0 += (double)w.x*x; a1 += (double)w.y*x;
          a2 += (double)w.z*x; a3 += (double)w.w*x;
        }
        double* pd = (double*)(A + 4096);
        pd[(cg*4+0)*64 + lt] = a0;
        pd[(cg*4+1)*64 + lt] = a1;
        pd[(cg*4+2)*64 + lt] = a2;
        pd[(cg*4+3)*64 + lt] = a3;
      }
      __syncthreads();                                 // bar6
      pzs_b[(size_t)widx*G4 + tid] = A[tid] + A[G4+tid] + A[2*G4+tid] + A[3*G4+tid];
      if (tid < 256){
        const double* pd = (const double*)(A + 4096);
        const int lt = tid >> 2, i = tid & 3;
        psums_b[(size_t)widx*H + tid] = pd[(0*4+i)*64 + lt] + pd[(1*4+i)*64 + lt]
                                      + pd[(2*4+i)*64 + lt] + pd[(3*4+i)*64 + lt];
      }
      __syncthreads();                                 // bar7
    }
  }
}

extern "C" void kernel_launch(void* const* d_in, const int* in_sizes, int n_in,
                              void* d_out, int out_size, void* d_ws, size_t ws_size,
                              hipStream_t stream){
  (void)in_sizes; (void)n_in; (void)out_size; (void)ws_size;
  const int*   tokens    = (const int*)  d_in[0];
  const float* word_emb  = (const float*)d_in[1];
  const float* compose_W = (const float*)d_in[2];
  const float* compose_b = (const float*)d_in[3];
  const float* h0        = (const float*)d_in[4];
  const float* c0        = (const float*)d_in[5];
  const float* pb_Wih    = (const float*)d_in[6];
  const float* pb_Whh    = (const float*)d_in[7];
  const float* pb_bih    = (const float*)d_in[8];
  const float* pb_bhh    = (const float*)d_in[9];
  const float* st_Wih    = (const float*)d_in[10];
  const float* st_Whh    = (const float*)d_in[11];
  const float* st_bih    = (const float*)d_in[12];
  const float* st_bhh    = (const float*)d_in[13];
  const float* hist_Wih  = (const float*)d_in[14];
  const float* hist_Whh  = (const float*)d_in[15];
  const float* hist_bih  = (const float*)d_in[16];
  const float* hist_bhh  = (const float*)d_in[17];
  const float* sum_W     = (const float*)d_in[18];
  const float* sum_b     = (const float*)d_in[19];
  const float* act_W     = (const float*)d_in[20];
  const float* act_b     = (const float*)d_in[21];
  const float* action_emb= (const float*)d_in[22];
  const int*   stack_map = (const int*)  d_in[23];
  const int*   buffer_map= (const int*)  d_in[24];

  float* ws     = (float*)d_ws;
  float* pb_zx  = ws;                                  // 128*64*1024 (arena-reused)
  float* st_zx  = pb_zx + (size_t)NB*SEQ*G4;           // 128*65*1024
  float* bufh   = st_zx + (size_t)NB*(SEQ+1)*G4;       // 128*64*256
  float* scst   = bufh  + (size_t)NB*SEQ*H;            // 128*41*256
  float* histxz = scst  + (size_t)NB*S1*H;             // 64*1024
  float* Wt_pb  = histxz + (size_t)NA*G4;              // [256][1024]
  float* Wt_st  = Wt_pb  + (size_t)H*G4;
  float* Wt_hi  = Wt_st  + (size_t)H*G4;
  float* Wt_sum = Wt_hi  + (size_t)H*G4;               // [768][256]
  float* Wt_act = Wt_sum + (size_t)768*H;              // [256][64]
  float* Wt_pbih= Wt_act + (size_t)H*NA;               // [128][1024]
  float* Wt_stih= Wt_pbih+ (size_t)DIN*G4;             // [128][1024]
  float* Wt_cmp = Wt_stih+ (size_t)DIN*G4;             // [256][128]
  float* ysumb  = Wt_cmp + (size_t)DE*DIN;             // [128][65][256]
  float* pz0    = ysumb  + (size_t)NB*65*H;            // [1024]
  double* psum0 = (double*)(pz0 + G4);                 // [256] f64
  float* ysumb0 = (float*)(psum0 + H);                 // [256]

  dim3 blk(32, 8);
  transpose_k<<<dim3(256/32, 1024/32), blk, 0, stream>>>(pb_Whh,   Wt_pb,  1024, 256);
  transpose_k<<<dim3(256/32, 1024/32), blk, 0, stream>>>(st_Whh,   Wt_st,  1024, 256);
  transpose_k<<<dim3(256/32, 1024/32), blk, 0, stream>>>(hist_Whh, Wt_hi,  1024, 256);
  transpose_k<<<dim3(768/32,  256/32), blk, 0, stream>>>(sum_W,    Wt_sum,  256, 768);
  transpose_k<<<dim3(256/32,   64/32), blk, 0, stream>>>(act_W,    Wt_act,   64, 256);
  transpose_k<<<dim3(128/32, 1024/32), blk, 0, stream>>>(pb_Wih,   Wt_pbih,1024, 128);
  transpose_k<<<dim3(128/32, 1024/32), blk, 0, stream>>>(st_Wih,   Wt_stih,1024, 128);
  transpose_k<<<dim3(256/32,  128/32), blk, 0, stream>>>(compose_W,Wt_cmp,  128, 256);
  hist_proj_kernel<<<dim3(NA), dim3(256), 0, stream>>>(hist_Wih, hist_bih, hist_bhh,
                                                       action_emb, histxz);
  h0_proj_kernel<<<dim3(1), dim3(256), 0, stream>>>(Wt_st, Wt_sum, h0, pz0, psum0, ysumb0);

  parser_kernel<<<dim3(NB), dim3(1024), 0, stream>>>(tokens, word_emb, Wt_cmp, compose_b,
      h0, c0, Wt_pbih, Wt_pb, pb_bih, pb_bhh, Wt_stih, Wt_st, st_bih, st_bhh,
      Wt_hi, Wt_sum, sum_b, Wt_act, act_b, stack_map, buffer_map,
      histxz, pb_zx, st_zx, bufh, scst, ysumb, pz0, psum0, ysumb0, (float*)d_out);
}

// Round 3
// 6403.345 us; speedup vs baseline: 1.6690x; 1.6690x over previous
//
#include <hip/hip_runtime.h>
#include <cmath>

constexpr int SEQ = 64;    // sequence length
constexpr int NB  = 128;   // batch
constexpr int H   = 256;   // hidden
constexpr int DIN = 128;   // composed token dim
constexpr int DE  = 256;   // word emb dim
constexpr int NA  = 64;    // actions
constexpr int S1  = 41;    // STACK_SIZE+1
constexpr int S2  = 42;    // slots incl trash slot 41 (unconditional writes)
constexpr int MS  = 100;   // max steps
constexpr int G4  = 1024;  // 4*H

__device__ __forceinline__ float sigf(float x){ return 1.0f/(1.0f+expf(-x)); }

// ---------------- transpose: in [R][C] -> out [C][R]
__global__ void transpose_k(const float* __restrict__ in, float* __restrict__ out,
                            int R, int C){
  __shared__ float t[32][33];
  int bx = blockIdx.x*32, by = blockIdx.y*32;
  int x = threadIdx.x, y = threadIdx.y;   // block 32x8
  #pragma unroll
  for (int j = 0; j < 32; j += 8)
    t[y+j][x] = in[(size_t)(by+y+j)*C + bx + x];
  __syncthreads();
  #pragma unroll
  for (int j = 0; j < 32; j += 8)
    out[(size_t)(bx+y+j)*R + by + x] = t[x][y+j];
}

// hist_xz[a][r] = hist_Wih[r,:] . action_emb[a,:] + hist_bih[r] + hist_bhh[r]
__global__ void hist_proj_kernel(const float* __restrict__ Wih,
                                 const float* __restrict__ bih,
                                 const float* __restrict__ bhh,
                                 const float* __restrict__ aemb,
                                 float* __restrict__ out){
  int a = blockIdx.x, t = threadIdx.x;
  __shared__ float e[64];
  if (t < 64) e[t] = aemb[a*64 + t];
  __syncthreads();
  for (int r = t; r < G4; r += blockDim.x){
    const float* w = Wih + r*64;
    float acc = bih[r] + bhh[r];
    #pragma unroll
    for (int k = 0; k < 64; k += 4)
      acc += w[k]*e[k] + w[k+1]*e[k+1] + w[k+2]*e[k+2] + w[k+3]*e[k+3];
    out[a*G4 + r] = acc;
  }
}

// one-time projections of h0:
// pz0 = st_Whh @ h0 ; psum0 = Wsum_s @ h0 (f64) ; ysumb0 = Wsum_b @ h0
__global__ void h0_proj_kernel(const float* __restrict__ Wt_st,   // [256][1024]
                               const float* __restrict__ Wt_sum,  // [768][256]
                               const float* __restrict__ h0,
                               float* __restrict__ pz0,           // [1024]
                               double* __restrict__ psum0,        // [256]
                               float* __restrict__ ysumb0){       // [256]
  __shared__ float h0l[H];
  const int t = threadIdx.x;   // 256 threads
  h0l[t] = h0[t];
  __syncthreads();
  float4 acc = make_float4(0.f,0.f,0.f,0.f);
  for (int c = 0; c < H; ++c){
    float4 w = ((const float4*)(Wt_st + (size_t)c*G4))[t];
    float x = h0l[c];
    acc.x += w.x*x; acc.y += w.y*x; acc.z += w.z*x; acc.w += w.w*x;
  }
  ((float4*)pz0)[t] = acc;
  double a0 = 0.0, a1 = 0.0;
  for (int c = 0; c < H; ++c){
    double x = (double)h0l[c];
    a0 += (double)Wt_sum[(size_t)c*H + t] * x;          // s-part
    a1 += (double)Wt_sum[(size_t)(H + c)*H + t] * x;    // b-part
  }
  psum0[t] = a0;
  ysumb0[t] = (float)a1;
}

// ---------------- prologue: per-element P0a/P0b/P1 + ysumb + slot-0 init.
// One block per batch element (128 blocks, 1024 threads). Verbatim round-1/2
// phase code (correctness-validated).
__global__ __launch_bounds__(1024, 1)
void prologue_kernel(const int* __restrict__ tokens,
                     const float* __restrict__ word_emb,
                     const float* __restrict__ Wt_cmp,   // [256][128]
                     const float* __restrict__ compose_b,
                     const float* __restrict__ h0,
                     const float* __restrict__ c0,
                     const float* __restrict__ Wt_pbih,  // [128][1024]
                     const float* __restrict__ Wt_pb,    // [256][1024]
                     const float* __restrict__ pb_bih,
                     const float* __restrict__ pb_bhh,
                     const float* __restrict__ Wt_stih,  // [128][1024]
                     const float* __restrict__ st_bih,
                     const float* __restrict__ st_bhh,
                     const float* __restrict__ Wt_sum,   // [768][256]
                     float* __restrict__ pb_zx,   // [B][64][1024]; arena reused for pzs/psums
                     float* __restrict__ st_zx,   // [B][65][1024] (row 64 = bias only)
                     float* __restrict__ bufh,    // [B][64][256]
                     float* __restrict__ scst,    // [B][42][256]
                     float* __restrict__ ysumb_g, // [B][65][256]
                     const float* __restrict__ pz0,
                     const double* __restrict__ psum0,
                     const float* __restrict__ ysumb0)
{
  __shared__ __align__(16) float A[8192];
  __shared__ __align__(16) float Bx[4096];
  __shared__ __align__(16) float ahl[H];
  __shared__ __align__(16) float acl[H];
  __shared__ __align__(16) float h0l[H];

  const int b   = blockIdx.x;
  const int tid = threadIdx.x;

  float* tokl = A;               // [64][128] during P0
  float* embs = Bx;              // [16][256] during P0a

  float*  pzs_b   = pb_zx + (size_t)b*SEQ*G4;
  double* psums_b = (double*)(pzs_b + (size_t)S2*G4);
  float*  pbzx_b  = pb_zx + (size_t)b*SEQ*G4;
  float*  stzx_b  = st_zx + (size_t)b*(SEQ+1)*G4;
  float*  bufh_b  = bufh  + (size_t)b*SEQ*H;
  float*  scst_b  = scst  + (size_t)b*S2*H;
  float*  ysumb_b = ysumb_g + (size_t)b*65*H;

  if (tid < H) h0l[tid] = h0[tid];
  __syncthreads();

  // ---------------- P0a
  {
    const int d = tid & 127, tb = tid >> 7;
    const float cb = compose_b[d];
    for (int pass = 0; pass < 4; ++pass){
      for (int j = tid >> 8; j < 16; j += 4){
        int tt = pass*16 + j;
        int id = tokens[tt*NB + b];
        embs[j*DE + (tid & 255)] = word_emb[(size_t)id*DE + (tid & 255)];
      }
      __syncthreads();
      float a0 = 0.f, a1 = 0.f;
      const float* eb = embs + (tb*2)*DE;
      for (int c = 0; c < DE; ++c){
        float w = Wt_cmp[c*DIN + d];
        a0 += w*eb[c]; a1 += w*eb[DE + c];
      }
      int t0 = pass*16 + tb*2;
      tokl[(t0    )*DIN + d] = fmaxf(a0 + cb, 0.f);
      tokl[(t0 + 1)*DIN + d] = fmaxf(a1 + cb, 0.f);
      __syncthreads();
    }
  }

  // ---------------- P0b
  {
    const int m  = tid >> 9;
    const int lt = tid & 255;
    const int sub = (tid >> 8) & 1;
    const float* Wt  = m ? Wt_stih : Wt_pbih;
    float*       zxb = m ? stzx_b : pbzx_b;
    const float* bA  = m ? st_bih : pb_bih;
    const float* bB  = m ? st_bhh : pb_bhh;
    float4 x1 = ((const float4*)bA)[lt], x2 = ((const float4*)bB)[lt];
    float bx = x1.x + x2.x, by = x1.y + x2.y, bz = x1.z + x2.z, bw = x1.w + x2.w;
    for (int blk = 0; blk < 4; ++blk){
      float ax[8], ay[8], az[8], aw[8];
      #pragma unroll
      for (int t = 0; t < 8; ++t){ ax[t]=0.f; ay[t]=0.f; az[t]=0.f; aw[t]=0.f; }
      const float* tb = tokl + (blk*16 + sub*8)*DIN;
      for (int c = 0; c < DIN; ++c){
        float4 w = ((const float4*)(Wt + (size_t)c*G4))[lt];
        #pragma unroll
        for (int t = 0; t < 8; ++t){
          float x = tb[t*DIN + c];
          ax[t] += w.x*x; ay[t] += w.y*x; az[t] += w.z*x; aw[t] += w.w*x;
        }
      }
      #pragma unroll
      for (int t = 0; t < 8; ++t){
        float4 r = make_float4(ax[t]+bx, ay[t]+by, az[t]+bz, aw[t]+bw);
        ((float4*)(zxb + (size_t)(blk*16 + sub*8 + t)*G4))[lt] = r;
      }
    }
    if (m == 1 && sub == 0)
      ((float4*)(zxb + (size_t)SEQ*G4))[lt] = make_float4(bx, by, bz, bw);
  }
  __syncthreads();

  // ---------------- P1: pre-buffer LSTM over reversed tokens
  if (tid < H){ ahl[tid] = h0l[tid]; acl[tid] = c0[tid]; }
  __syncthreads();
  for (int k = 0; k < SEQ; ++k){
    const int tt = SEQ - 1 - k;
    {
      const int q = tid & 255, cg = tid >> 8;
      float a0=0.f, a1=0.f, a2=0.f, a3=0.f;
      const int cb2 = cg*64;
      for (int c = cb2; c < cb2 + 64; ++c){
        float4 w = ((const float4*)(Wt_pb + (size_t)c*G4))[q];
        float x = ahl[c];
        a0 += w.x*x; a1 += w.y*x; a2 += w.z*x; a3 += w.w*x;
      }
      ((float4*)(A + cg*G4))[q] = make_float4(a0, a1, a2, a3);
    }
    __syncthreads();
    if (tid < H){
      const float* zx = pbzx_b + (size_t)tt*G4;
      float zi_ = A[tid]     + A[G4+tid]     + A[2*G4+tid]     + A[3*G4+tid]     + zx[tid];
      float zf_ = A[H+tid]   + A[G4+H+tid]   + A[2*G4+H+tid]   + A[3*G4+H+tid]   + zx[H+tid];
      float zg_ = A[2*H+tid] + A[G4+2*H+tid] + A[2*G4+2*H+tid] + A[3*G4+2*H+tid] + zx[2*H+tid];
      float zo_ = A[3*H+tid] + A[G4+3*H+tid] + A[2*G4+3*H+tid] + A[3*G4+3*H+tid] + zx[3*H+tid];
      float c2 = sigf(zf_)*acl[tid] + sigf(zi_)*tanhf(zg_);
      float h2 = sigf(zo_)*tanhf(c2);
      acl[tid] = c2; ahl[tid] = h2;
      bufh_b[(size_t)k*H + tid] = h2;
    }
    __syncthreads();
  }
  // pb_zx rows dead now; arena (pzs/psums) writable.

  // ---------------- slot-0 init + scst init
  if (tid < 256) ((float4*)pzs_b)[tid] = ((const float4*)pz0)[tid];
  if (tid < 256) psums_b[tid] = psum0[tid];
  if (tid < 64)  ((float4*)ysumb_b)[tid] = ((const float4*)ysumb0)[tid];
  for (int i = tid; i < S2*H; i += 1024) scst_b[i] = (i < H) ? c0[i] : 0.f;

  // ---------------- ysumb[j] = Wsum_b @ bufh[j-1], j=1..64 (f64 acc)
  {
    const int lt = tid & 63, wv = tid >> 6;
    double a00=0,a01=0,a02=0,a03=0, a10=0,a11=0,a12=0,a13=0;
    double a20=0,a21=0,a22=0,a23=0, a30=0,a31=0,a32=0,a33=0;
    for (int c = 0; c < H; ++c){
      float4 w = ((const float4*)(Wt_sum + (size_t)(H + c)*H))[lt];
      double x0 = (double)bufh_b[(size_t)(wv     )*H + c];
      double x1 = (double)bufh_b[(size_t)(wv + 16)*H + c];
      double x2 = (double)bufh_b[(size_t)(wv + 32)*H + c];
      double x3 = (double)bufh_b[(size_t)(wv + 48)*H + c];
      a00+=(double)w.x*x0; a01+=(double)w.y*x0; a02+=(double)w.z*x0; a03+=(double)w.w*x0;
      a10+=(double)w.x*x1; a11+=(double)w.y*x1; a12+=(double)w.z*x1; a13+=(double)w.w*x1;
      a20+=(double)w.x*x2; a21+=(double)w.y*x2; a22+=(double)w.z*x2; a23+=(double)w.w*x2;
      a30+=(double)w.x*x3; a31+=(double)w.y*x3; a32+=(double)w.z*x3; a33+=(double)w.w*x3;
    }
    ((float4*)(ysumb_b + (size_t)(wv+ 1)*H))[lt] = make_float4((float)a00,(float)a01,(float)a02,(float)a03);
    ((float4*)(ysumb_b + (size_t)(wv+17)*H))[lt] = make_float4((float)a10,(float)a11,(float)a12,(float)a13);
    ((float4*)(ysumb_b + (size_t)(wv+33)*H))[lt] = make_float4((float)a20,(float)a21,(float)a22,(float)a23);
    ((float4*)(ysumb_b + (size_t)(wv+49)*H))[lt] = make_float4((float)a30,(float)a31,(float)a32,(float)a33);
  }
}

// ---------------- main parser loop: 32 blocks x 1024 threads, 4 elements/block.
// Branch-free per-step phases (unconditional push-projection into dead/trash
// slots) keep all blocks in lockstep for cross-block L2 weight-stream sharing.
__global__ __launch_bounds__(1024, 1)
void step_kernel(const float* __restrict__ Wt_st,   // [256][1024]
                 const float* __restrict__ Wt_hi,   // [256][1024]
                 const float* __restrict__ Wt_sum,  // [768][256]
                 const float* __restrict__ Wt_act,  // [256][64]
                 const float* __restrict__ act_b,
                 const float* __restrict__ sum_b,
                 const int* __restrict__ stack_map,
                 const int* __restrict__ buffer_map,
                 const float* __restrict__ histxz,  // [64][1024]
                 const float* __restrict__ h0,
                 const float* __restrict__ c0,
                 float* __restrict__ pb_zx,         // arena: per-elem pzs[42][1024] + psums[42][256] f64
                 const float* __restrict__ st_zx,   // [B][65][1024]
                 float* __restrict__ scst,          // [B][42][256]
                 const float* __restrict__ ysumb_g, // [B][65][256]
                 float* __restrict__ out)           // [100][128][64]
{
  __shared__ __align__(16) float  ZH[4][1024];   // hist z partial-free outputs
  __shared__ __align__(16) double SU[4][256];    // suma (f64)
  __shared__ __align__(16) float  summ[4][256];
  __shared__ __align__(16) float  ahlT[256][4];  // [c][elem] for broadcast float4 reads
  __shared__ __align__(16) float  h2lT[256][4];
  __shared__ __align__(16) float  acl[4][256];
  __shared__ int ctl[4][8];   // per elem: 0 spos, 1 bpos, 2 sinc, 3 action, 5 widx_w

  const int tid = threadIdx.x;
  const int eL  = tid >> 8, rr = tid & 255;
  const int e0  = blockIdx.x * 4;
  const int e   = e0 + eL;

  float*  pzs_e   = pb_zx + (size_t)e*SEQ*G4;
  double* psums_e = (double*)(pzs_e + (size_t)S2*G4);
  const float* stzx_e  = st_zx   + (size_t)e*(SEQ+1)*G4;
  float*  scst_e  = scst    + (size_t)e*S2*H;
  const float* ysumb_e = ysumb_g + (size_t)e*65*H;

  ahlT[rr][eL] = h0[rr];
  acl[eL][rr]  = c0[rr];
  if (tid < 4){ ctl[tid][0] = 0; ctl[tid][1] = SEQ; ctl[tid][2] = SEQ - 1; }
  __syncthreads();

  for (int step = 0; step < MS; ++step){
    // ---- phase EA: (E) project prev-step h2 into slot caches; (A) hist z + suma
    if (step > 0){
      // E-f32: row tid of Wt_st, 4 elements from h2lT
      float a0=0.f,a1=0.f,a2=0.f,a3=0.f;
      for (int c = 0; c < H; c += 4){
        float w0 = Wt_st[(size_t)(c+0)*G4 + tid];
        float w1 = Wt_st[(size_t)(c+1)*G4 + tid];
        float w2 = Wt_st[(size_t)(c+2)*G4 + tid];
        float w3 = Wt_st[(size_t)(c+3)*G4 + tid];
        float4 x0 = *(const float4*)(&h2lT[c+0][0]);
        float4 x1 = *(const float4*)(&h2lT[c+1][0]);
        float4 x2 = *(const float4*)(&h2lT[c+2][0]);
        float4 x3 = *(const float4*)(&h2lT[c+3][0]);
        a0 += w0*x0.x + w1*x1.x + w2*x2.x + w3*x3.x;
        a1 += w0*x0.y + w1*x1.y + w2*x2.y + w3*x3.y;
        a2 += w0*x0.z + w1*x1.z + w2*x2.z + w3*x3.z;
        a3 += w0*x0.w + w1*x1.w + w2*x2.w + w3*x3.w;
      }
      (pb_zx + (size_t)(e0+0)*SEQ*G4)[(size_t)ctl[0][5]*G4 + tid] = a0;
      (pb_zx + (size_t)(e0+1)*SEQ*G4)[(size_t)ctl[1][5]*G4 + tid] = a1;
      (pb_zx + (size_t)(e0+2)*SEQ*G4)[(size_t)ctl[2][5]*G4 + tid] = a2;
      (pb_zx + (size_t)(e0+3)*SEQ*G4)[(size_t)ctl[3][5]*G4 + tid] = a3;
      // E-f64: psums projection for (eL, rr)
      double d = 0.0;
      for (int c = 0; c < H; ++c)
        d += (double)Wt_sum[(size_t)c*H + rr] * (double)h2lT[c][eL];
      psums_e[(size_t)ctl[eL][5]*H + rr] = d;
    }
    // A-f32: hist z, row tid of Wt_hi, 4 elements from ahlT
    {
      float a0=0.f,a1=0.f,a2=0.f,a3=0.f;
      for (int c = 0; c < H; c += 4){
        float w0 = Wt_hi[(size_t)(c+0)*G4 + tid];
        float w1 = Wt_hi[(size_t)(c+1)*G4 + tid];
        float w2 = Wt_hi[(size_t)(c+2)*G4 + tid];
        float w3 = Wt_hi[(size_t)(c+3)*G4 + tid];
        float4 x0 = *(const float4*)(&ahlT[c+0][0]);
        float4 x1 = *(const float4*)(&ahlT[c+1][0]);
        float4 x2 = *(const float4*)(&ahlT[c+2][0]);
        float4 x3 = *(const float4*)(&ahlT[c+3][0]);
        a0 += w0*x0.x + w1*x1.x + w2*x2.x + w3*x3.x;
        a1 += w0*x0.y + w1*x1.y + w2*x2.y + w3*x3.y;
        a2 += w0*x0.z + w1*x1.z + w2*x2.z + w3*x3.z;
        a3 += w0*x0.w + w1*x1.w + w2*x2.w + w3*x3.w;
      }
      ZH[0][tid]=a0; ZH[1][tid]=a1; ZH[2][tid]=a2; ZH[3][tid]=a3;
    }
    // A-f64: suma for (eL, rr)
    {
      double s = 0.0;
      for (int c = 0; c < H; ++c)
        s += (double)Wt_sum[(size_t)(512+c)*H + rr] * (double)ahlT[c][eL];
      SU[eL][rr] = s;
    }
    __syncthreads();                               // bar1

    // ---- preload slot-cache rows (regs) + B: summary
    const int spos  = ctl[eL][0], bposc = ctl[eL][1], sinc = ctl[eL][2];
    const float* pzr = pzs_e  + (size_t)spos*G4;
    const float* zxr = stzx_e + (size_t)sinc*G4;
    float g_pz0 = pzr[rr], g_pz1 = pzr[H+rr], g_pz2 = pzr[2*H+rr], g_pz3 = pzr[3*H+rr];
    float g_zx0 = zxr[rr], g_zx1 = zxr[H+rr], g_zx2 = zxr[2*H+rr], g_zx3 = zxr[3*H+rr];
    float g_ct = scst_e[(size_t)spos*H + rr];
    double g_ps = psums_e[(size_t)spos*H + rr];
    float g_yb = ysumb_e[(size_t)bposc*H + rr];
    {
      double s2 = SU[eL][rr] + g_ps + (double)g_yb + (double)sum_b[rr];
      summ[eL][rr] = fmaxf((float)s2, 0.f);
    }
    __syncthreads();                               // bar2

    // ---- C: logits (f64) + log_softmax + argmax + control (waves 0-3, 1 per elem)
    if (tid < 256){
      const int wv = tid >> 6, ln = tid & 63;
      double p0=0.0,p1=0.0,p2=0.0,p3=0.0;
      for (int c = 0; c < H; c += 4){
        p0 += (double)Wt_act[(c+0)*NA+ln] * (double)summ[wv][c+0];
        p1 += (double)Wt_act[(c+1)*NA+ln] * (double)summ[wv][c+1];
        p2 += (double)Wt_act[(c+2)*NA+ln] * (double)summ[wv][c+2];
        p3 += (double)Wt_act[(c+3)*NA+ln] * (double)summ[wv][c+3];
      }
      double acc = ((p0+p1)+(p2+p3)) + (double)act_b[ln];
      float v = (float)acc;
      float mx = v;
      #pragma unroll
      for (int o = 32; o > 0; o >>= 1) mx = fmaxf(mx, __shfl_xor(mx, o));
      float ex = expf(v - mx), sm = ex;
      #pragma unroll
      for (int o = 32; o > 0; o >>= 1) sm += __shfl_xor(sm, o);
      out[((size_t)step*NB + (e0+wv))*NA + ln] = v - mx - logf(sm);
      float bv = v; int bi = ln;   // argmax, first index wins on ties
      #pragma unroll
      for (int o = 32; o > 0; o >>= 1){
        float ov = __shfl_xor(bv, o); int oi = __shfl_xor(bi, o);
        if (ov > bv || (ov == bv && oi < bi)){ bv = ov; bi = oi; }
      }
      if (ln == 0){
        int a = bi;
        int sp = ctl[wv][0], bp = ctl[wv][1];
        int sop = stack_map[a], bop = buffer_map[a];
        if (sp == 0 && sop == -1) sop = 0;
        if (sp >= S1 - 1 && sop == 1) sop = 0;
        if (bp == 0 && bop == -1) bop = 0;
        int sposn = sp + sop;
        int bposn = bp + bop;
        int ne    = (bposn > 0) ? 1 : 0;
        int gidx  = bposn - 1; if (gidx < 0) gidx = 0; if (gidx > SEQ - 1) gidx = SEQ - 1;
        ctl[wv][3] = a;
        ctl[wv][5] = sp + 1;          // widx_w; 41 == trash slot when stack full
        ctl[wv][0] = sposn; ctl[wv][1] = bposn; ctl[wv][2] = ne ? gidx : SEQ;
      }
    }
    __syncthreads();                               // bar3

    // ---- D: st-LSTM gates (from preloaded regs) + hist-LSTM gates
    {
      const int a = ctl[eL][3], wdx = ctl[eL][5];
      float zi = g_pz0 + g_zx0, zf = g_pz1 + g_zx1;
      float zg = g_pz2 + g_zx2, zo = g_pz3 + g_zx3;
      float c2 = sigf(zf)*g_ct + sigf(zi)*tanhf(zg);
      float h2 = sigf(zo)*tanhf(c2);
      h2lT[rr][eL] = h2;
      scst_e[(size_t)wdx*H + rr] = c2;   // dead/trash-slot safe when no push
      const float* hb = histxz + (size_t)a*G4;
      float hi_ = ZH[eL][rr]      + hb[rr];
      float hf_ = ZH[eL][H+rr]    + hb[H+rr];
      float hg_ = ZH[eL][2*H+rr]  + hb[2*H+rr];
      float ho_ = ZH[eL][3*H+rr]  + hb[3*H+rr];
      float hc2 = sigf(hf_)*acl[eL][rr] + sigf(hi_)*tanhf(hg_);
      float hh2 = sigf(ho_)*tanhf(hc2);
      acl[eL][rr] = hc2; ahlT[rr][eL] = hh2;
    }
    __syncthreads();                               // bar4
  }
}

extern "C" void kernel_launch(void* const* d_in, const int* in_sizes, int n_in,
                              void* d_out, int out_size, void* d_ws, size_t ws_size,
                              hipStream_t stream){
  (void)in_sizes; (void)n_in; (void)out_size; (void)ws_size;
  const int*   tokens    = (const int*)  d_in[0];
  const float* word_emb  = (const float*)d_in[1];
  const float* compose_W = (const float*)d_in[2];
  const float* compose_b = (const float*)d_in[3];
  const float* h0        = (const float*)d_in[4];
  const float* c0        = (const float*)d_in[5];
  const float* pb_Wih    = (const float*)d_in[6];
  const float* pb_Whh    = (const float*)d_in[7];
  const float* pb_bih    = (const float*)d_in[8];
  const float* pb_bhh    = (const float*)d_in[9];
  const float* st_Wih    = (const float*)d_in[10];
  const float* st_Whh    = (const float*)d_in[11];
  const float* st_bih    = (const float*)d_in[12];
  const float* st_bhh    = (const float*)d_in[13];
  const float* hist_Wih  = (const float*)d_in[14];
  const float* hist_Whh  = (const float*)d_in[15];
  const float* hist_bih  = (const float*)d_in[16];
  const float* hist_bhh  = (const float*)d_in[17];
  const float* sum_W     = (const float*)d_in[18];
  const float* sum_b     = (const float*)d_in[19];
  const float* act_W     = (const float*)d_in[20];
  const float* act_b     = (const float*)d_in[21];
  const float* action_emb= (const float*)d_in[22];
  const int*   stack_map = (const int*)  d_in[23];
  const int*   buffer_map= (const int*)  d_in[24];

  float* ws     = (float*)d_ws;
  float* pb_zx  = ws;                                  // 128*64*1024 (arena: pzs[42]+psums[42] per elem)
  float* st_zx  = pb_zx + (size_t)NB*SEQ*G4;           // 128*65*1024
  float* bufh   = st_zx + (size_t)NB*(SEQ+1)*G4;       // 128*64*256
  float* scst   = bufh  + (size_t)NB*SEQ*H;            // 128*42*256
  float* histxz = scst  + (size_t)NB*S2*H;             // 64*1024
  float* Wt_pb  = histxz + (size_t)NA*G4;              // [256][1024]
  float* Wt_st  = Wt_pb  + (size_t)H*G4;
  float* Wt_hi  = Wt_st  + (size_t)H*G4;
  float* Wt_sum = Wt_hi  + (size_t)H*G4;               // [768][256]
  float* Wt_act = Wt_sum + (size_t)768*H;              // [256][64]
  float* Wt_pbih= Wt_act + (size_t)H*NA;               // [128][1024]
  float* Wt_stih= Wt_pbih+ (size_t)DIN*G4;             // [128][1024]
  float* Wt_cmp = Wt_stih+ (size_t)DIN*G4;             // [256][128]
  float* ysumb  = Wt_cmp + (size_t)DE*DIN;             // [128][65][256]
  float* pz0    = ysumb  + (size_t)NB*65*H;            // [1024]
  double* psum0 = (double*)(pz0 + G4);                 // [256] f64
  float* ysumb0 = (float*)(psum0 + H);                 // [256]

  dim3 blk(32, 8);
  transpose_k<<<dim3(256/32, 1024/32), blk, 0, stream>>>(pb_Whh,   Wt_pb,  1024, 256);
  transpose_k<<<dim3(256/32, 1024/32), blk, 0, stream>>>(st_Whh,   Wt_st,  1024, 256);
  transpose_k<<<dim3(256/32, 1024/32), blk, 0, stream>>>(hist_Whh, Wt_hi,  1024, 256);
  transpose_k<<<dim3(768/32,  256/32), blk, 0, stream>>>(sum_W,    Wt_sum,  256, 768);
  transpose_k<<<dim3(256/32,   64/32), blk, 0, stream>>>(act_W,    Wt_act,   64, 256);
  transpose_k<<<dim3(128/32, 1024/32), blk, 0, stream>>>(pb_Wih,   Wt_pbih,1024, 128);
  transpose_k<<<dim3(128/32, 1024/32), blk, 0, stream>>>(st_Wih,   Wt_stih,1024, 128);
  transpose_k<<<dim3(256/32,  128/32), blk, 0, stream>>>(compose_W,Wt_cmp,  128, 256);
  hist_proj_kernel<<<dim3(NA), dim3(256), 0, stream>>>(hist_Wih, hist_bih, hist_bhh,
                                                       action_emb, histxz);
  h0_proj_kernel<<<dim3(1), dim3(256), 0, stream>>>(Wt_st, Wt_sum, h0, pz0, psum0, ysumb0);

  prologue_kernel<<<dim3(NB), dim3(1024), 0, stream>>>(tokens, word_emb, Wt_cmp, compose_b,
      h0, c0, Wt_pbih, Wt_pb, pb_bih, pb_bhh, Wt_stih, st_bih, st_bhh, Wt_sum,
      pb_zx, st_zx, bufh, scst, ysumb, pz0, psum0, ysumb0);

  step_kernel<<<dim3(NB/4), dim3(1024), 0, stream>>>(Wt_st, Wt_hi, Wt_sum, Wt_act,
      act_b, sum_b, stack_map, buffer_map, histxz, h0, c0,
      pb_zx, st_zx, scst, ysumb, (float*)d_out);
}